// Round 8
// baseline (557.265 us; speedup 1.0000x reference)
//
#include <hip/hip_runtime.h>

#define NB 65536

typedef unsigned long long u64;
typedef __attribute__((ext_vector_type(8))) short short8;   // 8 bf16
typedef __attribute__((ext_vector_type(4))) float f32x4;

union FragAB { unsigned short us[8]; unsigned w[4]; short8 v; };
union WU     { uint4 u4; short8 v; };

__device__ __forceinline__ float sigf(float x){ return 1.0f/(1.0f + __expf(-x)); }
__device__ __forceinline__ float tanh_fast(float x){ return 1.0f - 2.0f/(1.0f + __expf(2.0f*x)); }

__device__ __forceinline__ unsigned short f2bf(float f){
    union { float f; unsigned u; } x; x.f = f;
    unsigned r = x.u + 0x7FFFu + ((x.u >> 16) & 1u);   // RNE
    return (unsigned short)(r >> 16);
}
__device__ __forceinline__ float bf2f(unsigned short h){
    union { unsigned u; float f; } x; x.u = ((unsigned)h) << 16; return x.f;
}

// ============ Kernel 0: one-time weight prep (unchanged layout) ============
__global__ __launch_bounds__(64)
void k_setup(const float* __restrict__ wih, const float* __restrict__ whh,
             const float* __restrict__ bih, const float* __restrict__ bhh,
             uint4* __restrict__ wtab, float4* __restrict__ btab)
{
    const int lane = threadIdx.x;
    const int q    = lane >> 4;
    const int n16  = lane & 15;
    #pragma unroll
    for (int m = 0; m < 6; ++m) {
        const int rowA = 16*m + n16;
        const int u    = rowA >> 2;
        const int gt   = rowA & 3;
        const float* wr = wih + (gt*24 + u)*33;
        FragAB fh, fl;
        #pragma unroll
        for (int j = 0; j < 8; ++j) {
            float v = wr[q*8 + j];
            unsigned short h = f2bf(v);
            fh.us[j] = h;
            fl.us[j] = f2bf(v - bf2f(h));
        }
        wtab[(m*4+0)*64 + lane] = make_uint4(fh.w[0], fh.w[1], fh.w[2], fh.w[3]);
        wtab[(m*4+1)*64 + lane] = make_uint4(fl.w[0], fl.w[1], fl.w[2], fl.w[3]);

        const float* hr = whh + (gt*24 + u)*24;
        FragAB gh, gl;
        #pragma unroll
        for (int j = 0; j < 8; ++j) {
            const int k = q*8 + j;
            float v = (k < 24) ? hr[k] : ((k == 24) ? wr[32] : 0.f);
            unsigned short h = f2bf(v);
            gh.us[j] = h;
            gl.us[j] = (k < 24) ? f2bf(v - bf2f(h)) : (unsigned short)0;
        }
        wtab[(m*4+2)*64 + lane] = make_uint4(gh.w[0], gh.w[1], gh.w[2], gh.w[3]);
        wtab[(m*4+3)*64 + lane] = make_uint4(gl.w[0], gl.w[1], gl.w[2], gl.w[3]);

        const int uu = 4*m + q;
        btab[m*64 + lane] = make_float4(bih[uu]      + bhh[uu],
                                        bih[24+uu]   + bhh[24+uu],
                                        bih[48+uu]   + bhh[48+uu],
                                        bih[72+uu]   + bhh[72+uu]);
    }
}

// ============ Fused kernel: conv+LIF (phase A) then MFMA LSTM + heads (phase B) ============
// 128 threads = 2 waves, 32 samples/block, 2048 blocks.
// Phase A: time-tiled conv (11 positions/superstep, threads = 32 samples x 4 pos-groups),
//          LIF chains (threads = 32 samples x 4 chain-groups of 8-9), all fp32, LDS-staged.
// Phase B: per-wave MFMA LSTM over 16 samples; spikes + avg come from LDS (no HBM trip).
// h-state: packed hi|lo dwords in hd[k][n] rows padded to 17 -> <=2-way banks everywhere.
__global__ __launch_bounds__(128)
void k_fused(const float* __restrict__ x,
             const float* __restrict__ c1w, const float* __restrict__ c1b,
             const float* __restrict__ b1g, const float* __restrict__ b1b,
             const float* __restrict__ b1m, const float* __restrict__ b1v,
             const float* __restrict__ c2w, const float* __restrict__ c2b,
             const float* __restrict__ b2g, const float* __restrict__ b2b,
             const float* __restrict__ b2m, const float* __restrict__ b2v,
             const uint4* __restrict__ wtab, const float4* __restrict__ btab,
             const float* __restrict__ rw1, const float* __restrict__ rb1,
             const float* __restrict__ rw2, const float* __restrict__ rb2,
             const float* __restrict__ fw,  const float* __restrict__ fb,
             const float* __restrict__ cw1, const float* __restrict__ cb1,
             const float* __restrict__ cw2, const float* __restrict__ cb2,
             float* __restrict__ out)
{
    __shared__ __align__(16) char smem[35584];
    float*    xs   = (float*)smem;                 // phase A: [32][65] staged x
    float*    hv   = (float*)(smem + 8320);        // phase A: [132][32] conv2 values
    u64*      spw  = (u64*)smem;                   // phase B: [32][32] packed spike words
    unsigned* hd2  = (unsigned*)(smem + 8192);     // phase B: [2][32][17] h hi|lo dwords
    float*    hf   = (float*)(smem + 12544);       // phase B: [2][16][24] final h
    unsigned* tml  = (unsigned*)(smem + 25216);    // [33][32] spike timelines
    float*    pavg = (float*)(smem + 29440);       // [12][4][32] avg partials

    const int tid  = threadIdx.x;
    const int sm   = tid & 31;          // sample within block
    const int pgg  = tid >> 5;          // 0..3: pos-group / chain-group / t-group
    const int bidx = blockIdx.x * 32 + sm;

    // fold conv1 bias + bn1 (identical op order to prior rounds)
    float w1f[6][5], c1f[6];
    #pragma unroll
    for (int c = 0; c < 6; ++c) {
        float s = b1g[c] / sqrtf(b1v[c] + 1e-5f);
        #pragma unroll
        for (int j = 0; j < 5; ++j) w1f[c][j] = c1w[c*5+j] * s;
        c1f[c] = (c1b[c] - b1m[c]) * s + b1b[c];
    }
    float s2v[12], t2v[12], sum12[12];
    #pragma unroll
    for (int c = 0; c < 12; ++c) {
        float s = b2g[c] / sqrtf(b2v[c] + 1e-5f);
        s2v[c] = s;
        t2v[c] = (c2b[c] - b2m[c]) * s + b2b[c];
        sum12[c] = 0.f;
    }

    // LIF state: chains kk = pgg + 4*j (j<8); pgg==0 also owns chain 32 (j==8)
    float m1[9], m2[9];
    unsigned tb[9];
    #pragma unroll
    for (int j = 0; j < 9; ++j) { m1[j] = 0.f; m2[j] = 0.f; tb[j] = 0u; }

    // ================= phase A =================
    #pragma unroll 1
    for (int ss = 0; ss < 8; ++ss) {
        // stage x[44ss-4 .. 44ss+60) for 32 samples (coalesced reads, 2-way LDS writes)
        #pragma unroll
        for (int r = 0; r < 4; ++r) {
            const int id   = tid + 128*r;
            const int samp = id >> 4;
            const int ch   = id & 15;
            const int gi   = 44*ss - 4 + 4*ch;
            float4 v;
            if (gi >= 0 && gi <= 356)
                v = *(const float4*)(x + (size_t)(blockIdx.x*32 + samp)*360 + gi);
            else
                v = make_float4(0.f,0.f,0.f,0.f);
            const int base = samp*65 + 4*ch;
            xs[base+0]=v.x; xs[base+1]=v.y; xs[base+2]=v.z; xs[base+3]=v.w;
        }
        __syncthreads();

        // conv: 3 passes, pg = pgg + 4*pass (skip pg==11)
        #pragma unroll
        for (int pass = 0; pass < 3; ++pass) {
            const int pg = pgg + 4*pass;
            if (pg < 11) {
                const int p = 11*ss + pg;
                float xw[9];
                #pragma unroll
                for (int k2 = 0; k2 < 9; ++k2) xw[k2] = xs[sm*65 + 4*pg + k2];

                float hA[6], hB[6], hC[6];
                const bool valid = (p > 0);
                #pragma unroll
                for (int c = 0; c < 6; ++c) {
                    float aA = c1f[c] + w1f[c][0]*xw[0] + w1f[c][1]*xw[1]
                             + w1f[c][2]*xw[2] + w1f[c][3]*xw[3] + w1f[c][4]*xw[4];
                    float aB = c1f[c] + w1f[c][0]*xw[2] + w1f[c][1]*xw[3]
                             + w1f[c][2]*xw[4] + w1f[c][3]*xw[5] + w1f[c][4]*xw[6];
                    float aC = c1f[c] + w1f[c][0]*xw[4] + w1f[c][1]*xw[5]
                             + w1f[c][2]*xw[6] + w1f[c][3]*xw[7] + w1f[c][4]*xw[8];
                    hA[c] = valid ? fmaxf(aA, 0.f) : 0.f;
                    hB[c] = fmaxf(aB, 0.f);
                    hC[c] = fmaxf(aC, 0.f);
                }
                #pragma unroll
                for (int c2 = 0; c2 < 12; ++c2) {
                    float acc = 0.f;
                    #pragma unroll
                    for (int c1 = 0; c1 < 6; ++c1) {
                        const float* wp = c2w + c2*18 + c1*3;
                        acc += wp[0]*hA[c1] + wp[1]*hB[c1] + wp[2]*hC[c1];
                    }
                    float hvv = fmaxf(acc*s2v[c2] + t2v[c2], 0.f);
                    sum12[c2] += hvv;
                    hv[(12*pg + c2)*32 + sm] = hvv;
                }
            }
        }
        __syncthreads();

        // LIF: 4 timesteps, chains pgg+4j
        #pragma unroll
        for (int tl = 0; tl < 4; ++tl) {
            const int t = 4*ss + tl;
            #pragma unroll
            for (int j = 0; j < 9; ++j) {
                if (j < 8 || pgg == 0) {
                    const int kk = (j < 8) ? (pgg + 4*j) : 32;
                    const float v = hv[(33*tl + kk)*32 + sm];
                    m1[j] = 0.95f*m1[j] + v;
                    float s1 = (m1[j] > 0.5f) ? 1.f : 0.f;
                    m1[j] *= (1.f - s1);
                    float v2 = 0.9f*m2[j] + s1;
                    bool s2 = (v2 > 0.6f);
                    m2[j] = s2 ? 0.f : v2;
                    if (s2) tb[j] |= (1u << t);
                }
            }
        }
        __syncthreads();   // hv reads done before next superstep overwrites
    }

    // tail positions 88 (pgg==0) and 89 (pgg==1): avg only, direct global reads
    if (pgg < 2) {
        const int p = 88 + pgg;
        const int xbase = 4*p - 4;
        float xw[12];
        #pragma unroll
        for (int e = 0; e < 3; ++e) {
            const int gi = xbase + 4*e;
            float4 v;
            if (gi <= 356) v = *(const float4*)(x + (size_t)bidx*360 + gi);
            else           v = make_float4(0.f,0.f,0.f,0.f);
            xw[4*e+0]=v.x; xw[4*e+1]=v.y; xw[4*e+2]=v.z; xw[4*e+3]=v.w;
        }
        float hA[6], hB[6], hC[6];
        #pragma unroll
        for (int c = 0; c < 6; ++c) {
            float aA = c1f[c] + w1f[c][0]*xw[0] + w1f[c][1]*xw[1]
                     + w1f[c][2]*xw[2] + w1f[c][3]*xw[3] + w1f[c][4]*xw[4];
            float aB = c1f[c] + w1f[c][0]*xw[2] + w1f[c][1]*xw[3]
                     + w1f[c][2]*xw[4] + w1f[c][3]*xw[5] + w1f[c][4]*xw[6];
            float aC = c1f[c] + w1f[c][0]*xw[4] + w1f[c][1]*xw[5]
                     + w1f[c][2]*xw[6] + w1f[c][3]*xw[7] + w1f[c][4]*xw[8];
            hA[c] = fmaxf(aA, 0.f);
            hB[c] = fmaxf(aB, 0.f);
            hC[c] = fmaxf(aC, 0.f);
        }
        #pragma unroll
        for (int c2 = 0; c2 < 12; ++c2) {
            float acc = 0.f;
            #pragma unroll
            for (int c1 = 0; c1 < 6; ++c1) {
                const float* wp = c2w + c2*18 + c1*3;
                acc += wp[0]*hA[c1] + wp[1]*hB[c1] + wp[2]*hC[c1];
            }
            sum12[c2] += fmaxf(acc*s2v[c2] + t2v[c2], 0.f);
        }
    }

    // publish timelines + avg partials
    #pragma unroll
    for (int j = 0; j < 9; ++j) {
        if (j < 8 || pgg == 0) {
            const int kk = (j < 8) ? (pgg + 4*j) : 32;
            tml[kk*32 + sm] = tb[j];
        }
    }
    #pragma unroll
    for (int c2 = 0; c2 < 12; ++c2) pavg[(c2*4 + pgg)*32 + sm] = sum12[c2];
    __syncthreads();

    // ================= transition: pack spike words, zero h-state =================
    {
        // thread (sm, pgg) builds spw[t][sm] for t = 8*pgg .. 8*pgg+7
        u64 w[8];
        #pragma unroll
        for (int tt = 0; tt < 8; ++tt) w[tt] = 0ull;
        #pragma unroll
        for (int kk = 0; kk < 33; ++kk) {
            const unsigned r = tml[kk*32 + sm];
            #pragma unroll
            for (int tt = 0; tt < 8; ++tt)
                w[tt] |= (u64)((r >> (8*pgg + tt)) & 1u) << kk;
        }
        #pragma unroll
        for (int tt = 0; tt < 8; ++tt)
            spw[(8*pgg + tt)*32 + sm] = w[tt];
    }
    #pragma unroll
    for (int i = 0; i < 9; ++i) {          // zero hd2: 1088 dwords
        const int idx = tid + 128*i;
        if (idx < 1088) hd2[idx] = 0u;
    }

    // load MFMA fragments (coalesced, prebuilt) — overlaps with the sync
    const int lane = tid & 63;
    const int wv   = tid >> 6;
    const int q    = lane >> 4;
    const int n16  = lane & 15;
    short8 WihHi[6], WihLo[6], WhhHi[6], WhhLo[6];
    float4 bias[6];
    #pragma unroll
    for (int m = 0; m < 6; ++m) {
        WU a0, a1, a2, a3;
        a0.u4 = wtab[(m*4+0)*64 + lane];
        a1.u4 = wtab[(m*4+1)*64 + lane];
        a2.u4 = wtab[(m*4+2)*64 + lane];
        a3.u4 = wtab[(m*4+3)*64 + lane];
        WihHi[m] = a0.v; WihLo[m] = a1.v; WhhHi[m] = a2.v; WhhLo[m] = a3.v;
        bias[m] = btab[m*64 + lane];
    }
    __syncthreads();   // spw + hd2 visible to both waves

    // ================= phase B: MFMA LSTM (per-wave, 16 samples) =================
    unsigned* hdw = hd2 + wv*544;          // this wave's [32][17] h-state
    const int sl  = 16*wv + n16;           // block-local sample

    float cst[6], hreg[6];
    #pragma unroll
    for (int m = 0; m < 6; ++m) { cst[m] = 0.f; hreg[m] = 0.f; }

    u64 wcur = spw[sl];                    // t = 0

    #pragma unroll 1
    for (int t = 0; t < 32; ++t) {
        // h B-fragments: 8 b32 reads (2-way banks), repack hi/lo
        unsigned d[8];
        #pragma unroll
        for (int j = 0; j < 8; ++j) d[j] = hdw[(8*q + j)*17 + n16];

        const unsigned lo32 = (unsigned)wcur;
        const unsigned hi32 = (unsigned)(wcur >> 32);

        u64 wnext = 0;
        if (t < 31) wnext = spw[(t+1)*32 + sl];

        FragAB bhHi, bhLo;
        #pragma unroll
        for (int p = 0; p < 4; ++p) {
            bhHi.w[p] = (d[2*p] & 0xFFFFu) | (d[2*p+1] << 16);
            bhLo.w[p] = (d[2*p] >> 16)     | (d[2*p+1] & 0xFFFF0000u);
        }
        // q==3, slot k=24 (zero row) carries spike bit 32 (pairs with wih[:,32] in WhhHi)
        if (q == 3) bhHi.w[0] |= (hi32 & 1u) ? 0x3F80u : 0u;

        FragAB bs0;
        {
            const unsigned byt = (lo32 >> (q*8)) & 0xFFu;
            #pragma unroll
            for (int p = 0; p < 4; ++p) {
                unsigned e0 = (byt >> (2*p)) & 1u;
                unsigned e1 = (byt >> (2*p+1)) & 1u;
                bs0.w[p] = (e0 ? 0x3F80u : 0u) | (e1 ? 0x3F800000u : 0u);
            }
        }

        f32x4 acc[6];
        #pragma unroll
        for (int m = 0; m < 6; ++m) {
            f32x4 a; a[0]=bias[m].x; a[1]=bias[m].y; a[2]=bias[m].z; a[3]=bias[m].w;
            a = __builtin_amdgcn_mfma_f32_16x16x32_bf16(WihHi[m], bs0.v,  a, 0, 0, 0);
            a = __builtin_amdgcn_mfma_f32_16x16x32_bf16(WihLo[m], bs0.v,  a, 0, 0, 0);
            a = __builtin_amdgcn_mfma_f32_16x16x32_bf16(WhhHi[m], bhHi.v, a, 0, 0, 0);
            a = __builtin_amdgcn_mfma_f32_16x16x32_bf16(WhhLo[m], bhHi.v, a, 0, 0, 0);
            a = __builtin_amdgcn_mfma_f32_16x16x32_bf16(WhhHi[m], bhLo.v, a, 0, 0, 0);
            acc[m] = a;
        }

        #pragma unroll
        for (int m = 0; m < 6; ++m) {
            float ii = sigf(acc[m][0]);
            float ff = sigf(acc[m][1]);
            float gg = tanh_fast(acc[m][2]);
            float oo = sigf(acc[m][3]);
            float cn = ff*cst[m] + ii*gg;
            cst[m] = cn;
            float h = oo * tanh_fast(cn);
            hreg[m] = h;
            unsigned short hh = f2bf(h);
            unsigned short hl = f2bf(h - bf2f(hh));
            hdw[(4*m + q)*17 + n16] = (unsigned)hh | ((unsigned)hl << 16);
        }
        __asm__ volatile("s_waitcnt lgkmcnt(0)" ::: "memory");  // intra-wave ds RAW
        wcur = wnext;
    }

    // publish final h (fp32) for the head phase (intra-wave)
    #pragma unroll
    for (int m = 0; m < 6; ++m) hf[(wv*16 + n16)*24 + 4*m + q] = hreg[m];
    __asm__ volatile("s_waitcnt lgkmcnt(0)" ::: "memory");

    // ================= heads (lane<16 of each wave handles its 16 samples) =================
    if (lane < 16) {
        const int sm2 = lane;
        const int bo  = blockIdx.x * 32 + wv*16 + sm2;
        float h[24];
        #pragma unroll
        for (int u2 = 0; u2 < 24; ++u2) h[u2] = hf[(wv*16 + sm2)*24 + u2];
        float av[12];
        #pragma unroll
        for (int cc = 0; cc < 12; ++cc) {
            const int s = 16*wv + sm2;
            av[cc] = (pavg[(cc*4+0)*32 + s] + pavg[(cc*4+1)*32 + s]
                    + pavg[(cc*4+2)*32 + s] + pavg[(cc*4+3)*32 + s]) / 90.0f;
        }

        float f1[12];
        #pragma unroll
        for (int r = 0; r < 12; ++r) {
            float a = rb1[r];
            #pragma unroll
            for (int u2 = 0; u2 < 24; ++u2) a += rw1[r*36+u2]*h[u2];
            #pragma unroll
            for (int cc = 0; cc < 12; ++cc) a += rw1[r*36+24+cc]*av[cc];
            f1[r] = fmaxf(a, 0.f);
        }
        float z0 = rb2[0], z1 = rb2[1];
        #pragma unroll
        for (int r = 0; r < 12; ++r) { z0 += rw2[r]*f1[r]; z1 += rw2[12+r]*f1[r]; }
        float mz = fmaxf(z0, z1);
        float e0 = __expf(z0 - mz), e1 = __expf(z1 - mz);
        float inv = 1.0f/(e0 + e1);
        float r0 = 0.7f*e0*inv, r1 = 0.3f*e1*inv;
        float alpha = r0/(r0 + r1);

        float ha[24], sa[12];
        #pragma unroll
        for (int u2 = 0; u2 < 24; ++u2) ha[u2] = h[u2]*alpha;
        #pragma unroll
        for (int cc = 0; cc < 12; ++cc) sa[cc] = av[cc]*(1.f - alpha);

        float fu[24];
        #pragma unroll
        for (int r = 0; r < 24; ++r) {
            float a = fb[r];
            #pragma unroll
            for (int u2 = 0; u2 < 24; ++u2) a += fw[r*36+u2]*ha[u2];
            #pragma unroll
            for (int cc = 0; cc < 12; ++cc) a += fw[r*36+24+cc]*sa[cc];
            fu[r] = fmaxf(a, 0.f);
        }
        float c1o[12];
        #pragma unroll
        for (int r = 0; r < 12; ++r) {
            float a = cb1[r];
            #pragma unroll
            for (int u2 = 0; u2 < 24; ++u2) a += cw1[r*24+u2]*fu[u2];
            c1o[r] = fmaxf(a, 0.f);
        }
        #pragma unroll
        for (int o = 0; o < 5; ++o) {
            float a = cb2[o];
            #pragma unroll
            for (int r = 0; r < 12; ++r) a += cw2[o*12+r]*c1o[r];
            out[(size_t)bo*5 + o] = a;
        }
    }
}

extern "C" void kernel_launch(void* const* d_in, const int* in_sizes, int n_in,
                              void* d_out, int out_size, void* d_ws, size_t ws_size,
                              hipStream_t stream) {
    const float* x    = (const float*)d_in[0];
    const float* c1w  = (const float*)d_in[1];
    const float* c1b  = (const float*)d_in[2];
    const float* b1g  = (const float*)d_in[3];
    const float* b1b  = (const float*)d_in[4];
    const float* b1m  = (const float*)d_in[5];
    const float* b1v  = (const float*)d_in[6];
    const float* c2w  = (const float*)d_in[7];
    const float* c2b  = (const float*)d_in[8];
    const float* b2g  = (const float*)d_in[9];
    const float* b2b  = (const float*)d_in[10];
    const float* b2m  = (const float*)d_in[11];
    const float* b2v  = (const float*)d_in[12];
    const float* wih  = (const float*)d_in[13];
    const float* whh  = (const float*)d_in[14];
    const float* bih  = (const float*)d_in[15];
    const float* bhh  = (const float*)d_in[16];
    const float* rw1  = (const float*)d_in[17];
    const float* rb1  = (const float*)d_in[18];
    const float* rw2  = (const float*)d_in[19];
    const float* rb2  = (const float*)d_in[20];
    const float* fw   = (const float*)d_in[21];
    const float* fb   = (const float*)d_in[22];
    const float* cw1  = (const float*)d_in[23];
    const float* cb1  = (const float*)d_in[24];
    const float* cw2  = (const float*)d_in[25];
    const float* cb2  = (const float*)d_in[26];
    float* out = (float*)d_out;

    char* ws = (char*)d_ws;
    uint4*  wtab = (uint4*)ws;                      // 24 KB
    float4* btab = (float4*)(ws + 24*64*16);        // 6 KB

    k_setup<<<dim3(1), dim3(64), 0, stream>>>(wih, whh, bih, bhh, wtab, btab);
    k_fused<<<dim3(NB/32), dim3(128), 0, stream>>>(x, c1w, c1b, b1g, b1b, b1m, b1v,
                                                   c2w, c2b, b2g, b2b, b2m, b2v,
                                                   wtab, btab,
                                                   rw1, rb1, rw2, rb2, fw, fb,
                                                   cw1, cb1, cw2, cb2, out);
}